// Round 15
// baseline (172.234 us; speedup 1.0000x reference)
//
#include <hip/hip_runtime.h>
#include <math.h>

#define N_NODES 10000
#define N_EDGES 160000
#define RT1 157      // ceil(10000/64)
#define RTE 2500     // 160000/64
#define CONVX_T (RT1 * 64 * 32)   // 321536
#define MAXSEG 16
#define SEGSTRIDE 576             // bytes: 512 pacc(bf16x256) + 32 m(f32x8) + 32 den(f32x8)

static inline int ceildiv(int a, int b) { return (a + b - 1) / b; }

typedef float f32x4 __attribute__((ext_vector_type(4)));
typedef short bf16x8 __attribute__((ext_vector_type(8)));

__device__ __forceinline__ unsigned short f2bf(float f) {
  unsigned int u = __builtin_bit_cast(unsigned int, f);
  u += 0x7FFFu + ((u >> 16) & 1u);   // RNE
  return (unsigned short)(u >> 16);
}
__device__ __forceinline__ float bf2f(unsigned short h) {
  unsigned int u = ((unsigned int)h) << 16;
  return __builtin_bit_cast(float, u);
}

// ---------------- prep ----------------
__global__ void count_kernel(const int* __restrict__ dstp, int* __restrict__ deg, int E) {
  for (int i = blockIdx.x * blockDim.x + threadIdx.x; i < E; i += gridDim.x * blockDim.x)
    atomicAdd(&deg[dstp[i]], 1);
}

__global__ void scan_kernel(const int* __restrict__ deg, int* __restrict__ rowptr, int n) {
  __shared__ int part[1024];
  const int tid = threadIdx.x;
  const int CHK = 10;
  int base = tid * CHK;
  int loc[CHK];
  int s = 0;
#pragma unroll
  for (int j = 0; j < CHK; ++j) {
    int idx = base + j;
    int v = (idx < n) ? deg[idx] : 0;
    loc[j] = s; s += v;
  }
  part[tid] = s;
  __syncthreads();
  for (int off = 1; off < 1024; off <<= 1) {
    int y = (tid >= off) ? part[tid - off] : 0;
    __syncthreads();
    part[tid] += y;
    __syncthreads();
  }
  int pre = tid ? part[tid - 1] : 0;
#pragma unroll
  for (int j = 0; j < CHK; ++j) {
    int idx = base + j;
    if (idx < n) rowptr[idx] = pre + loc[j];
  }
  if (tid == 1023) rowptr[n] = part[1023];
}

// sorted-order side arrays: srcs, dsts, eid, rel_s
__global__ void scatter_kernel(const float* __restrict__ lu, const float* __restrict__ tt,
                               const int* __restrict__ srcp, const int* __restrict__ dstp,
                               const int* __restrict__ rowptr, int* __restrict__ fill,
                               int* __restrict__ srcs, int* __restrict__ dsts,
                               int* __restrict__ eidA, float* __restrict__ rel_s, int E) {
  for (int e = blockIdx.x * blockDim.x + threadIdx.x; e < E; e += gridDim.x * blockDim.x) {
    int d = dstp[e], s = srcp[e];
    int pos = atomicAdd(&fill[d], 1);
    int slot = rowptr[d] + pos;
    srcs[slot] = s;
    dsts[slot] = d;
    eidA[slot] = e;
    rel_s[slot] = lu[s] - tt[e];
  }
}

// ---------------- all format conversions in ONE launch ----------------
__device__ __forceinline__ void wstore(const float* __restrict__ W, unsigned short* __restrict__ out,
                                       int Nin, int n_off, int NFtot, int k, int c) {
  int gc = n_off + c;
  int ks=k>>5, kg=(k>>3)&3, j=k&7, nf=gc>>4, ic=gc&15;
  out[(size_t)(ks*NFtot+nf)*512 + (ic+16*kg)*8 + j] = f2bf(W[(size_t)k*Nin + c]);
}

__global__ void conv_all_kernel(const float* __restrict__ x, unsigned short* __restrict__ xa,
                                const float* Wq1, const float* Wk1, const float* Wv1, const float* Ws1,
                                const float* We1, const float* Wq2, const float* Wk2, const float* Wv2,
                                const float* Ws2, const float* We2,
                                const float* bq1, const float* bk1, const float* bv1, const float* bs1,
                                const float* bq2, const float* bk2, const float* bv2, const float* bs2,
                                unsigned short* W1f, unsigned short* We1f, unsigned short* W2f,
                                unsigned short* We2f, float* bcat1, float* bcat2) {
  int t0 = blockIdx.x * blockDim.x + threadIdx.x;
  if (t0 < CONVX_T) {
    int i = t0 >> 5, k8 = t0 & 31;
    union { uint4 q; unsigned short s[8]; } u;
    if (i < N_NODES) {
      const float4* px = (const float4*)(x + (size_t)i * 256 + k8 * 8);
      float4 f0 = px[0], f1 = px[1];
      u.s[0]=f2bf(f0.x); u.s[1]=f2bf(f0.y); u.s[2]=f2bf(f0.z); u.s[3]=f2bf(f0.w);
      u.s[4]=f2bf(f1.x); u.s[5]=f2bf(f1.y); u.s[6]=f2bf(f1.z); u.s[7]=f2bf(f1.w);
    } else {
      u.q = make_uint4(0,0,0,0);
    }
    int rt=i>>6, rf=(i>>4)&3, ir=i&15, ks=k8>>2, kg=k8&3;
    *(uint4*)&xa[(size_t)rt*16384 + ks*2048 + rf*512 + (ir+16*kg)*8] = u.q;
    return;
  }
  int t = t0 - CONVX_T;
  if (t < 262144) {               // W1f: 4 x 256x256
    int w = t >> 16, r = t & 65535, k = r >> 8, c = r & 255;
    const float* W = (w == 0) ? Wq1 : (w == 1) ? Wk1 : (w == 2) ? Wv1 : Ws1;
    wstore(W, W1f, 256, w * 256, 64, k, c);
  } else if (t < 327680) {        // We1f: 256x256
    int r = t - 262144, k = r >> 8, c = r & 255;
    wstore(We1, We1f, 256, 0, 16, k, c);
  } else if (t < 360448) {        // W2f: 4 x 256x32
    int r = t - 327680, w = r >> 13, r2 = r & 8191, k = r2 >> 5, c = r2 & 31;
    const float* W = (w == 0) ? Wq2 : (w == 1) ? Wk2 : (w == 2) ? Wv2 : Ws2;
    wstore(W, W2f, 32, w * 32, 8, k, c);
  } else if (t < 368640) {        // We2f: 256x32 (cols 32-63 pre-zeroed by memset)
    int r = t - 360448, k = r >> 5, c = r & 31;
    wstore(We2, We2f, 32, 0, 4, k, c);
  } else if (t < 369792) {        // biases
    int r = t - 368640;
    if (r < 1024) {
      const float* b = (r < 256) ? bq1 : (r < 512) ? bk1 : (r < 768) ? bv1 : bs1;
      bcat1[r] = b[r & 255];
    } else {
      int r2 = r - 1024;
      const float* b = (r2 < 32) ? bq2 : (r2 < 64) ? bk2 : (r2 < 96) ? bv2 : bs2;
      bcat2[r2] = b[r2 & 31];
    }
  }
}

// ---------------- node1 GEMM (SEPARATE launch — edge_fused consumes qf/kvb) ----------------
__global__ __launch_bounds__(512, 4)
void node1_gemm(const unsigned short* __restrict__ xa, const unsigned short* __restrict__ W1f,
                const float* __restrict__ bcat1, float* __restrict__ qf,
                unsigned short* __restrict__ kvb, float* __restrict__ sf) {
  __shared__ char ldsraw[32768];
  uint4* lds4 = (uint4*)ldsraw;
  const int tid = threadIdx.x;
  const int wid = tid >> 6, lane = tid & 63;
  const int fr0 = (lane >> 4) * 4;
  const int fc0 = lane & 15;
  const int rt0 = blockIdx.x % RT1;
  const int y = blockIdx.x / RT1;              // 0..3: q | k | v | s
  const int phase = rt0 & 7;

#pragma unroll
  for (int s = 0; s < 4; ++s)
    lds4[tid + s * 512] = *(const uint4*)(xa + (size_t)rt0 * 16384 + (size_t)(tid + s * 512) * 8);
  __syncthreads();

  f32x4 acc[4][2];
#pragma unroll
  for (int i = 0; i < 4; ++i)
#pragma unroll
    for (int j = 0; j < 2; ++j) acc[i][j] = (f32x4){0.f, 0.f, 0.f, 0.f};

  bf16x8 aN0, aN1, aN2, aN3, bN0, bN1;
  {
    const int ks = phase;
    aN0 = *(const bf16x8*)&lds4[ks * 256 + 0 * 64 + lane];
    aN1 = *(const bf16x8*)&lds4[ks * 256 + 1 * 64 + lane];
    aN2 = *(const bf16x8*)&lds4[ks * 256 + 2 * 64 + lane];
    aN3 = *(const bf16x8*)&lds4[ks * 256 + 3 * 64 + lane];
    bN0 = *(const bf16x8*)(W1f + ((size_t)(ks * 64 + y * 16 + wid * 2 + 0)) * 512 + (size_t)lane * 8);
    bN1 = *(const bf16x8*)(W1f + ((size_t)(ks * 64 + y * 16 + wid * 2 + 1)) * 512 + (size_t)lane * 8);
  }
#pragma unroll
  for (int ksi = 0; ksi < 8; ++ksi) {
    bf16x8 aC0 = aN0, aC1 = aN1, aC2 = aN2, aC3 = aN3;
    bf16x8 bC0 = bN0, bC1 = bN1;
    if (ksi < 7) {
      const int ks2 = (ksi + 1) ^ phase;
      aN0 = *(const bf16x8*)&lds4[ks2 * 256 + 0 * 64 + lane];
      aN1 = *(const bf16x8*)&lds4[ks2 * 256 + 1 * 64 + lane];
      aN2 = *(const bf16x8*)&lds4[ks2 * 256 + 2 * 64 + lane];
      aN3 = *(const bf16x8*)&lds4[ks2 * 256 + 3 * 64 + lane];
      bN0 = *(const bf16x8*)(W1f + ((size_t)(ks2 * 64 + y * 16 + wid * 2 + 0)) * 512 + (size_t)lane * 8);
      bN1 = *(const bf16x8*)(W1f + ((size_t)(ks2 * 64 + y * 16 + wid * 2 + 1)) * 512 + (size_t)lane * 8);
    }
    acc[0][0] = __builtin_amdgcn_mfma_f32_16x16x32_bf16(aC0, bC0, acc[0][0], 0, 0, 0);
    acc[1][0] = __builtin_amdgcn_mfma_f32_16x16x32_bf16(aC1, bC0, acc[1][0], 0, 0, 0);
    acc[2][0] = __builtin_amdgcn_mfma_f32_16x16x32_bf16(aC2, bC0, acc[2][0], 0, 0, 0);
    acc[3][0] = __builtin_amdgcn_mfma_f32_16x16x32_bf16(aC3, bC0, acc[3][0], 0, 0, 0);
    acc[0][1] = __builtin_amdgcn_mfma_f32_16x16x32_bf16(aC0, bC1, acc[0][1], 0, 0, 0);
    acc[1][1] = __builtin_amdgcn_mfma_f32_16x16x32_bf16(aC1, bC1, acc[1][1], 0, 0, 0);
    acc[2][1] = __builtin_amdgcn_mfma_f32_16x16x32_bf16(aC2, bC1, acc[2][1], 0, 0, 0);
    acc[3][1] = __builtin_amdgcn_mfma_f32_16x16x32_bf16(aC3, bC1, acc[3][1], 0, 0, 0);
  }

  bool bf16path;
  void* dstp_; int cstr_, dc0_, bcol0_;
  if (y == 0)      { bf16path = false; dstp_ = qf;  cstr_ = 256; dc0_ = 0;   bcol0_ = 0; }
  else if (y == 1) { bf16path = true;  dstp_ = kvb; cstr_ = 512; dc0_ = 0;   bcol0_ = 256; }
  else if (y == 2) { bf16path = true;  dstp_ = kvb; cstr_ = 512; dc0_ = 256; bcol0_ = 512; }
  else             { bf16path = false; dstp_ = sf;  cstr_ = 256; dc0_ = 0;   bcol0_ = 768; }
  if (!bf16path) {
    float* dst = (float*)dstp_;
    const int row0 = rt0 * 64 + fr0;
#pragma unroll
    for (int cf = 0; cf < 2; ++cf) {
      int c = wid * 32 + cf * 16 + fc0;
      float bv = bcat1[bcol0_ + c];
#pragma unroll
      for (int rf = 0; rf < 4; ++rf) {
#pragma unroll
        for (int j = 0; j < 4; ++j) {
          int r = row0 + rf * 16 + j;
          if (r < N_NODES) dst[(size_t)r * cstr_ + c] = acc[rf][cf][j] + bv;
        }
      }
    }
  } else {
    __syncthreads();
    unsigned short* cl = (unsigned short*)ldsraw;   // [64][72]
    unsigned short* dst = (unsigned short*)dstp_;
    for (int pass = 0; pass < 4; ++pass) {
      if ((wid >> 1) == pass) {
#pragma unroll
        for (int cf = 0; cf < 2; ++cf) {
          int c = (wid & 1) * 32 + cf * 16 + fc0;
          float bv = bcat1[bcol0_ + pass * 64 + c];
#pragma unroll
          for (int rf = 0; rf < 4; ++rf)
#pragma unroll
            for (int j = 0; j < 4; ++j)
              cl[(fr0 + rf * 16 + j) * 72 + c] = f2bf(acc[rf][cf][j] + bv);
        }
      }
      __syncthreads();
      {
        int row = tid >> 3, cc = (tid & 7) * 8;
        int gr = rt0 * 64 + row;
        if (gr < N_NODES)
          *(uint4*)&dst[(size_t)gr * cstr_ + dc0_ + pass * 64 + cc] = *(const uint4*)&cl[row * 72 + cc];
      }
      __syncthreads();
    }
  }
}

// ---------------- edge GEMM + FUSED layer-1 attention ----------------
// R15: split prologue (T14): msg global->regs issued FIRST; cos -> LDS steps 0-3;
// barrier; K-steps 0-3 (MFMA hides msg HBM latency); msg regs -> LDS steps 4-7;
// barrier; K-steps 4-7. In-wave attention epilogue (R14) unchanged.
__global__ __launch_bounds__(512, 4)
void edge_fused(const float* __restrict__ qf, const unsigned short* __restrict__ kvb,
                const unsigned short* __restrict__ We1f, const unsigned short* __restrict__ We2f,
                char* __restrict__ segrec, unsigned short* __restrict__ e2b,
                const float* __restrict__ rel_s, const float* __restrict__ tw,
                const float* __restrict__ tb, const float* __restrict__ msg,
                const int* __restrict__ eidA, const int* __restrict__ srcsA,
                const int* __restrict__ dstsA, const int* __restrict__ rowptr) {
  __shared__ char ldsraw[38912];
  uint4* lds4 = (uint4*)ldsraw;                               // K-loop A tile (32KB)
  unsigned short* e1t = (unsigned short*)ldsraw;              // [64][260] epilogue
  int* dseg     = (int*)(ldsraw + 33280);                     // [64]
  int* sseg     = (int*)(ldsraw + 33536);                     // [64]
  unsigned short* cl2 = (unsigned short*)(ldsraw + 33792);    // [64][40]

  const int tid = threadIdx.x;
  const int wid = tid >> 6, lane = tid & 63;
  const int bx = blockIdx.x;
  const int fr0 = (lane >> 4) * 4;
  const int fc0 = lane & 15;
  const int rt0 = bx;

  // ---- prologue: msg loads in flight; cos -> LDS steps 0-3; dseg/sseg ----
  const int rem = tid & 255;
  const int ksh = tid >> 8;                // 0 or 1
  float4 mA0, mA1, mB0, mB1;
  {
    const int arf = rem >> 6, ar2 = rem & 63, air = ar2 & 15, akg = ar2 >> 4;
    const int slot = rt0 * 64 + arf * 16 + air;
    int eorg = eidA[slot];
    // issue msg loads FIRST (latency hides under cos VALU + K-part1 MFMA)
    const float4* pmA = (const float4*)(msg + (size_t)eorg * 128 + (size_t)(ksh * 4 + akg) * 8);
    mA0 = pmA[0]; mA1 = pmA[1];                           // for ks = 4 + ksh
    const float4* pmB = (const float4*)(msg + (size_t)eorg * 128 + (size_t)((2 + ksh) * 4 + akg) * 8);
    mB0 = pmB[0]; mB1 = pmB[1];                           // for ks = 6 + ksh
    if (tid < 64) {
      dseg[tid] = dstsA[rt0 * 64 + tid];
      sseg[tid] = srcsA[rt0 * 64 + tid];
    }
    float rl = rel_s[slot];
#pragma unroll
    for (int s = 0; s < 2; ++s) {
      int ks = ksh + s * 2;                // cos K-steps 0..3
      int k8 = ks * 4 + akg;
      const float4* twp = (const float4*)(tw + k8 * 8);
      const float4* tbp = (const float4*)(tb + k8 * 8);
      float4 w0 = twp[0], w1 = twp[1], b0 = tbp[0], b1 = tbp[1];
      union { uint4 q; unsigned short us[8]; } u;
      u.us[0]=f2bf(__cosf(rl*w0.x+b0.x)); u.us[1]=f2bf(__cosf(rl*w0.y+b0.y));
      u.us[2]=f2bf(__cosf(rl*w0.z+b0.z)); u.us[3]=f2bf(__cosf(rl*w0.w+b0.w));
      u.us[4]=f2bf(__cosf(rl*w1.x+b1.x)); u.us[5]=f2bf(__cosf(rl*w1.y+b1.y));
      u.us[6]=f2bf(__cosf(rl*w1.z+b1.z)); u.us[7]=f2bf(__cosf(rl*w1.w+b1.w));
      lds4[ks * 256 + rem] = u.q;
    }
  }
  __syncthreads();

  f32x4 acc[4][2];
  f32x4 acc2[4];
#pragma unroll
  for (int i = 0; i < 4; ++i) {
    acc2[i] = (f32x4){0.f, 0.f, 0.f, 0.f};
#pragma unroll
    for (int j = 0; j < 2; ++j) acc[i][j] = (f32x4){0.f, 0.f, 0.f, 0.f};
  }

  // ---- K-loop part 1 (cos steps 0-3), 1-step B pipeline ----
  bf16x8 bN0, bN1, b2N;
  bN0 = *(const bf16x8*)(We1f + ((size_t)(0 * 16 + wid * 2 + 0)) * 512 + (size_t)lane * 8);
  bN1 = *(const bf16x8*)(We1f + ((size_t)(0 * 16 + wid * 2 + 1)) * 512 + (size_t)lane * 8);
  b2N = 0;
  if (wid < 2) b2N = *(const bf16x8*)(We2f + ((size_t)(0 * 4 + wid)) * 512 + (size_t)lane * 8);
#pragma unroll
  for (int ks = 0; ks < 4; ++ks) {
    bf16x8 bC0 = bN0, bC1 = bN1, b2C = b2N;
    if (ks < 3) {
      bN0 = *(const bf16x8*)(We1f + ((size_t)((ks + 1) * 16 + wid * 2 + 0)) * 512 + (size_t)lane * 8);
      bN1 = *(const bf16x8*)(We1f + ((size_t)((ks + 1) * 16 + wid * 2 + 1)) * 512 + (size_t)lane * 8);
      if (wid < 2) b2N = *(const bf16x8*)(We2f + ((size_t)((ks + 1) * 4 + wid)) * 512 + (size_t)lane * 8);
    }
    bf16x8 a0 = *(const bf16x8*)&lds4[ks * 256 + 0 * 64 + lane];
    bf16x8 a1 = *(const bf16x8*)&lds4[ks * 256 + 1 * 64 + lane];
    bf16x8 a2 = *(const bf16x8*)&lds4[ks * 256 + 2 * 64 + lane];
    bf16x8 a3 = *(const bf16x8*)&lds4[ks * 256 + 3 * 64 + lane];
    acc[0][0] = __builtin_amdgcn_mfma_f32_16x16x32_bf16(a0, bC0, acc[0][0], 0, 0, 0);
    acc[1][0] = __builtin_amdgcn_mfma_f32_16x16x32_bf16(a1, bC0, acc[1][0], 0, 0, 0);
    acc[2][0] = __builtin_amdgcn_mfma_f32_16x16x32_bf16(a2, bC0, acc[2][0], 0, 0, 0);
    acc[3][0] = __builtin_amdgcn_mfma_f32_16x16x32_bf16(a3, bC0, acc[3][0], 0, 0, 0);
    acc[0][1] = __builtin_amdgcn_mfma_f32_16x16x32_bf16(a0, bC1, acc[0][1], 0, 0, 0);
    acc[1][1] = __builtin_amdgcn_mfma_f32_16x16x32_bf16(a1, bC1, acc[1][1], 0, 0, 0);
    acc[2][1] = __builtin_amdgcn_mfma_f32_16x16x32_bf16(a2, bC1, acc[2][1], 0, 0, 0);
    acc[3][1] = __builtin_amdgcn_mfma_f32_16x16x32_bf16(a3, bC1, acc[3][1], 0, 0, 0);
    if (wid < 2) {
      acc2[0] = __builtin_amdgcn_mfma_f32_16x16x32_bf16(a0, b2C, acc2[0], 0, 0, 0);
      acc2[1] = __builtin_amdgcn_mfma_f32_16x16x32_bf16(a1, b2C, acc2[1], 0, 0, 0);
      acc2[2] = __builtin_amdgcn_mfma_f32_16x16x32_bf16(a2, b2C, acc2[2], 0, 0, 0);
      acc2[3] = __builtin_amdgcn_mfma_f32_16x16x32_bf16(a3, b2C, acc2[3], 0, 0, 0);
    }
  }

  // write msg regs -> LDS steps 4-7; prefetch B for ks=4
  bN0 = *(const bf16x8*)(We1f + ((size_t)(4 * 16 + wid * 2 + 0)) * 512 + (size_t)lane * 8);
  bN1 = *(const bf16x8*)(We1f + ((size_t)(4 * 16 + wid * 2 + 1)) * 512 + (size_t)lane * 8);
  if (wid < 2) b2N = *(const bf16x8*)(We2f + ((size_t)(4 * 4 + wid)) * 512 + (size_t)lane * 8);
  {
    union { uint4 q; unsigned short us[8]; } u;
    u.us[0]=f2bf(mA0.x); u.us[1]=f2bf(mA0.y); u.us[2]=f2bf(mA0.z); u.us[3]=f2bf(mA0.w);
    u.us[4]=f2bf(mA1.x); u.us[5]=f2bf(mA1.y); u.us[6]=f2bf(mA1.z); u.us[7]=f2bf(mA1.w);
    lds4[(4 + ksh) * 256 + rem] = u.q;
    u.us[0]=f2bf(mB0.x); u.us[1]=f2bf(mB0.y); u.us[2]=f2bf(mB0.z); u.us[3]=f2bf(mB0.w);
    u.us[4]=f2bf(mB1.x); u.us[5]=f2bf(mB1.y); u.us[6]=f2bf(mB1.z); u.us[7]=f2bf(mB1.w);
    lds4[(6 + ksh) * 256 + rem] = u.q;
  }
  __syncthreads();

  // ---- K-loop part 2 (msg steps 4-7) ----
#pragma unroll
  for (int ks = 4; ks < 8; ++ks) {
    bf16x8 bC0 = bN0, bC1 = bN1, b2C = b2N;
    if (ks < 7) {
      bN0 = *(const bf16x8*)(We1f + ((size_t)((ks + 1) * 16 + wid * 2 + 0)) * 512 + (size_t)lane * 8);
      bN1 = *(const bf16x8*)(We1f + ((size_t)((ks + 1) * 16 + wid * 2 + 1)) * 512 + (size_t)lane * 8);
      if (wid < 2) b2N = *(const bf16x8*)(We2f + ((size_t)((ks + 1) * 4 + wid)) * 512 + (size_t)lane * 8);
    }
    bf16x8 a0 = *(const bf16x8*)&lds4[ks * 256 + 0 * 64 + lane];
    bf16x8 a1 = *(const bf16x8*)&lds4[ks * 256 + 1 * 64 + lane];
    bf16x8 a2 = *(const bf16x8*)&lds4[ks * 256 + 2 * 64 + lane];
    bf16x8 a3 = *(const bf16x8*)&lds4[ks * 256 + 3 * 64 + lane];
    acc[0][0] = __builtin_amdgcn_mfma_f32_16x16x32_bf16(a0, bC0, acc[0][0], 0, 0, 0);
    acc[1][0] = __builtin_amdgcn_mfma_f32_16x16x32_bf16(a1, bC0, acc[1][0], 0, 0, 0);
    acc[2][0] = __builtin_amdgcn_mfma_f32_16x16x32_bf16(a2, bC0, acc[2][0], 0, 0, 0);
    acc[3][0] = __builtin_amdgcn_mfma_f32_16x16x32_bf16(a3, bC0, acc[3][0], 0, 0, 0);
    acc[0][1] = __builtin_amdgcn_mfma_f32_16x16x32_bf16(a0, bC1, acc[0][1], 0, 0, 0);
    acc[1][1] = __builtin_amdgcn_mfma_f32_16x16x32_bf16(a1, bC1, acc[1][1], 0, 0, 0);
    acc[2][1] = __builtin_amdgcn_mfma_f32_16x16x32_bf16(a2, bC1, acc[2][1], 0, 0, 0);
    acc[3][1] = __builtin_amdgcn_mfma_f32_16x16x32_bf16(a3, bC1, acc[3][1], 0, 0, 0);
    if (wid < 2) {
      acc2[0] = __builtin_amdgcn_mfma_f32_16x16x32_bf16(a0, b2C, acc2[0], 0, 0, 0);
      acc2[1] = __builtin_amdgcn_mfma_f32_16x16x32_bf16(a1, b2C, acc2[1], 0, 0, 0);
      acc2[2] = __builtin_amdgcn_mfma_f32_16x16x32_bf16(a2, b2C, acc2[2], 0, 0, 0);
      acc2[3] = __builtin_amdgcn_mfma_f32_16x16x32_bf16(a3, b2C, acc2[3], 0, 0, 0);
    }
  }

  // ---- epilogue: dump e1/e2, ONE barrier, then all in-wave (R14) ----
  __syncthreads();   // A-tile reads done; reuse LDS
#pragma unroll
  for (int cf = 0; cf < 2; ++cf)
#pragma unroll
    for (int rf = 0; rf < 4; ++rf)
#pragma unroll
      for (int j = 0; j < 4; ++j)
        e1t[(fr0 + rf * 16 + j) * 260 + wid * 32 + cf * 16 + fc0] = f2bf(acc[rf][cf][j]);
  if (wid < 2) {
#pragma unroll
    for (int rf = 0; rf < 4; ++rf)
#pragma unroll
      for (int j = 0; j < 4; ++j)
        cl2[(fr0 + rf * 16 + j) * 40 + wid * 16 + fc0] = f2bf(acc2[rf][j]);
  }
  __syncthreads();

  // e2b store first (independent, writes in flight early)
  if (tid < 256) {
    int row = tid >> 2, cc = (tid & 3) * 8;
    *(uint4*)&e2b[(size_t)(rt0 * 64 + row) * 32 + cc] = *(const uint4*)&cl2[row * 40 + cc];
  }

  // ---- in-wave fused attention: wave wid owns rows [wid*8, wid*8+8) ----
  {
    const int base = wid * 8;
    const int rgj = bx * 8 + wid;
    int d8[8], s8[8];
#pragma unroll
    for (int t = 0; t < 8; ++t) { d8[t] = dseg[base + t]; s8[t] = sseg[base + t]; }

    float4 q8[8]; ushort4 k8[8], e8[8];
#pragma unroll
    for (int t = 0; t < 8; ++t) {
      q8[t] = *(const float4*)&qf[(size_t)d8[t] * 256 + lane * 4];
      k8[t] = *(const ushort4*)&kvb[(size_t)s8[t] * 512 + lane * 4];
      e8[t] = *(const ushort4*)&e1t[(base + t) * 260 + lane * 4];
    }
    float sc[8];
#pragma unroll
    for (int t = 0; t < 8; ++t) {
      float p = q8[t].x * (bf2f(k8[t].x) + bf2f(e8[t].x))
              + q8[t].y * (bf2f(k8[t].y) + bf2f(e8[t].y))
              + q8[t].z * (bf2f(k8[t].z) + bf2f(e8[t].z))
              + q8[t].w * (bf2f(k8[t].w) + bf2f(e8[t].w));
      p += __shfl_xor(p, 1); p += __shfl_xor(p, 2); p += __shfl_xor(p, 4);
      sc[t] = p * 0.17677669529663687f;
    }
    ushort4 v8[8];
#pragma unroll
    for (int t = 0; t < 8; ++t)
      v8[t] = *(const ushort4*)&kvb[(size_t)s8[t] * 512 + 256 + lane * 4];

    float m8[8], w8[8];
#pragma unroll
    for (int t = 0; t < 8; ++t) {
      float mm = sc[t];
#pragma unroll
      for (int u = 0; u < 8; ++u)
        if (d8[u] == d8[t]) mm = fmaxf(mm, sc[u]);
      m8[t] = mm;
      w8[t] = __expf(sc[t] - mm);
    }
#pragma unroll
    for (int t = 0; t < 8; ++t) {
      bool first = (t == 0) || (d8[t - 1] != d8[t]);
      if (first && (lane & 7) == 0) {
        float den = 0.f;
#pragma unroll
        for (int u = 0; u < 8; ++u)
          if (d8[u] == d8[t]) den += w8[u];
        int j = rgj - (rowptr[d8[t]] >> 3);
        if (j < MAXSEG) {
          float* rec = (float*)(segrec + ((size_t)d8[t] * MAXSEG + j) * SEGSTRIDE);
          rec[128 + (lane >> 3)] = m8[t];
          rec[136 + (lane >> 3)] = den;
        }
      }
    }
    f32x4 pacc = (f32x4){0.f, 0.f, 0.f, 0.f};
    int cur = d8[0];
#pragma unroll
    for (int t = 0; t < 8; ++t) {
      if (d8[t] != cur) {
        int j = rgj - (rowptr[cur] >> 3);
        if (j < MAXSEG) {
          unsigned short* pp = (unsigned short*)(segrec + ((size_t)cur * MAXSEG + j) * SEGSTRIDE);
          ushort4 o;
          o.x = f2bf(pacc[0]); o.y = f2bf(pacc[1]); o.z = f2bf(pacc[2]); o.w = f2bf(pacc[3]);
          *(ushort4*)&pp[lane * 4] = o;
        }
        pacc = (f32x4){0.f, 0.f, 0.f, 0.f};
        cur = d8[t];
      }
      pacc[0] += w8[t] * (bf2f(v8[t].x) + bf2f(e8[t].x));
      pacc[1] += w8[t] * (bf2f(v8[t].y) + bf2f(e8[t].y));
      pacc[2] += w8[t] * (bf2f(v8[t].z) + bf2f(e8[t].z));
      pacc[3] += w8[t] * (bf2f(v8[t].w) + bf2f(e8[t].w));
    }
    {
      int j = rgj - (rowptr[cur] >> 3);
      if (j < MAXSEG) {
        unsigned short* pp = (unsigned short*)(segrec + ((size_t)cur * MAXSEG + j) * SEGSTRIDE);
        ushort4 o;
        o.x = f2bf(pacc[0]); o.y = f2bf(pacc[1]); o.z = f2bf(pacc[2]); o.w = f2bf(pacc[3]);
        *(ushort4*)&pp[lane * 4] = o;
      }
    }
  }
}

// ---------------- node2 fused: merge segments -> h (LDS frag tile) -> GEMM ----------------
// Block = one 64-node row tile; 256 threads (4 waves).
__global__ __launch_bounds__(256)
void node2_fused(const char* __restrict__ segrec, const int* __restrict__ rowptr,
                 const float* __restrict__ sf, const unsigned short* __restrict__ W2f,
                 const float* __restrict__ bcat2, float* __restrict__ qkvs2) {
  __shared__ unsigned short haL[8 * 2048];   // 32KB, frag layout: ks*2048 + rf*512 + (ir+16*kg)*8 + j
  const int tid = threadIdx.x;
  const int wid = tid >> 6, lane = tid & 63;
  const int rt0 = blockIdx.x;

  // ---- merge phase: thread t -> node rt0*64+(t>>2), cols (t&3)*64 .. +63 ----
  {
    const int nl = tid >> 2;
    const int n = rt0 * 64 + nl;
    const int cb = (tid & 3) * 64;
    const int rf = (nl >> 4) & 3, ir = nl & 15;
    if (n < N_NODES) {
      const int beg = rowptr[n], end = rowptr[n + 1];
      int s0 = 0, span = 0;
      if (beg < end) {
        s0 = beg >> 3;
        span = ((end - 1) >> 3) - s0 + 1;
        if (span > MAXSEG) span = MAXSEG;
      }
#pragma unroll
      for (int cc = 0; cc < 4; ++cc) {            // 16-col chunks
        const int c0 = cb + cc * 16;
        const int h = c0 >> 5;
        float o[16];
        if (span == 0) {
#pragma unroll
          for (int q = 0; q < 16; ++q) o[q] = 0.f;
        } else {
          float M = -INFINITY;
          for (int j = 0; j < span; ++j) {
            const float* rec = (const float*)(segrec + ((size_t)n * MAXSEG + j) * SEGSTRIDE);
            M = fmaxf(M, rec[128 + h]);
          }
          float den = 0.f;
#pragma unroll
          for (int q = 0; q < 16; ++q) o[q] = 0.f;
          for (int j = 0; j < span; ++j) {
            const float* rec = (const float*)(segrec + ((size_t)n * MAXSEG + j) * SEGSTRIDE);
            float scj = __expf(rec[128 + h] - M);
            den += scj * rec[136 + h];
            const unsigned short* pp = (const unsigned short*)rec;
#pragma unroll
            for (int q4 = 0; q4 < 4; ++q4) {
              ushort4 p4 = *(const ushort4*)&pp[c0 + q4 * 4];
              o[q4*4+0] += scj * bf2f(p4.x); o[q4*4+1] += scj * bf2f(p4.y);
              o[q4*4+2] += scj * bf2f(p4.z); o[q4*4+3] += scj * bf2f(p4.w);
            }
          }
          const float inv = 1.f / (den + 1e-16f);
#pragma unroll
          for (int q = 0; q < 16; ++q) o[q] *= inv;
        }
        // + skip, relu, write to frag LDS
#pragma unroll
        for (int q4 = 0; q4 < 4; ++q4) {
          const int c = c0 + q4 * 4;
          float4 sk = *(const float4*)&sf[(size_t)n * 256 + c];
          ushort4 w4;
          w4.x = f2bf(fmaxf(o[q4*4+0] + sk.x, 0.f));
          w4.y = f2bf(fmaxf(o[q4*4+1] + sk.y, 0.f));
          w4.z = f2bf(fmaxf(o[q4*4+2] + sk.z, 0.f));
          w4.w = f2bf(fmaxf(o[q4*4+3] + sk.w, 0.f));
          int ks = c >> 5, kg = (c >> 3) & 3, j = c & 7;
          *(ushort4*)&haL[ks * 2048 + rf * 512 + (ir + 16 * kg) * 8 + j] = w4;
        }
      }
    } else {
      // pad rows -> zero
#pragma unroll
      for (int cc = 0; cc < 4; ++cc) {
        const int c0 = cb + cc * 16;
#pragma unroll
        for (int q4 = 0; q4 < 4; ++q4) {
          const int c = c0 + q4 * 4;
          int ks = c >> 5, kg = (c >> 3) & 3, j = c & 7;
          ushort4 z; z.x = z.y = z.z = z.w = 0;
          *(ushort4*)&haL[ks * 2048 + rf * 512 + (ir + 16 * kg) * 8 + j] = z;
        }
      }
    }
  }
  __syncthreads();

  // ---- GEMM: wave wid -> cols [wid*32, wid*32+32), rows all 64 ----
  f32x4 acc[4][2];
#pragma unroll
  for (int i = 0; i < 4; ++i)
#pragma unroll
    for (int j = 0; j < 2; ++j) acc[i][j] = (f32x4){0.f, 0.f, 0.f, 0.f};

#pragma unroll
  for (int ks = 0; ks < 8; ++ks) {
    bf16x8 a[4], b[2];
#pragma unroll
    for (int rf = 0; rf < 4; ++rf)
      a[rf] = *(const bf16x8*)&haL[ks * 2048 + (rf * 64 + lane) * 8];
#pragma unroll
    for (int cf = 0; cf < 2; ++cf)
      b[cf] = *(const bf16x8*)(W2f + ((size_t)(ks * 8 + wid * 2 + cf)) * 512 + (size_t)lane * 8);
#pragma unroll
    for (int rf = 0; rf < 4; ++rf)
#pragma unroll
      for (int cf = 0; cf < 2; ++cf)
        acc[rf][cf] = __builtin_amdgcn_mfma_f32_16x16x32_bf16(a[rf], b[cf], acc[rf][cf], 0, 0, 0);
  }

  const int row0 = rt0 * 64 + ((lane >> 4) * 4);
  const int cb2 = wid * 32 + (lane & 15);
#pragma unroll
  for (int cf = 0; cf < 2; ++cf) {
    int c = cb2 + cf * 16;
    float bv = bcat2[c];
#pragma unroll
    for (int rf = 0; rf < 4; ++rf) {
#pragma unroll
      for (int j = 0; j < 4; ++j) {
        int r = row0 + rf * 16 + j;
        if (r < N_NODES) qkvs2[(size_t)r * 128 + c] = acc[rf][cf][j] + bv;
      }
    }
  }
}

// ---------------- attention layer 2: 4 nodes / 256-thread block ----------------
__global__ __launch_bounds__(256)
void attn2_kernel(const float* __restrict__ qkvs2, const unsigned short* __restrict__ e2b,
                  const int* __restrict__ srcs, const int* __restrict__ rowptr,
                  float* __restrict__ outp) {
  const int n = blockIdx.x * 4 + (threadIdx.x >> 6);
  if (n >= N_NODES) return;
  const int lane = threadIdx.x & 63;
  const int c = lane & 31;
  const int beg = rowptr[n], end = rowptr[n + 1];
  const float qv = qkvs2[(size_t)n * 128 + c];

  float m0=-INFINITY,d0=0,x0=0;
  float m1=-INFINITY,d1=0,x1=0;
  float m2=-INFINITY,d2=0,x2=0;
  float m3=-INFINITY,d3=0,x3=0;

  auto step = [&](int i, float& m, float& d, float& a) {
    const int s = srcs[i];
    const float ev = bf2f(e2b[(size_t)i * 32 + c]);
    float p = qv * (qkvs2[(size_t)s * 128 + 32 + c] + ev);
    const float v = qkvs2[(size_t)s * 128 + 64 + c] + ev;
#pragma unroll
    for (int off = 16; off; off >>= 1) p += __shfl_xor(p, off);
    p *= 0.17677669529663687f;
    const float mn = fmaxf(m, p);
    const float sc = __expf(m - mn), w = __expf(p - mn);
    d = d * sc + w; a = a * sc + w * v; m = mn;
  };

  int i = beg;
  for (; i + 3 < end; i += 4) {
    step(i, m0, d0, x0);
    step(i + 1, m1, d1, x1);
    step(i + 2, m2, d2, x2);
    step(i + 3, m3, d3, x3);
  }
  for (; i < end; ++i) step(i, m0, d0, x0);

  auto merge = [&](float& m, float& d, float& a, float mB, float dB, float b) {
    if (mB == -INFINITY) return;
    const float M = fmaxf(m, mB);
    const float sA = __expf(m - M), sB = __expf(mB - M);
    d = d * sA + dB * sB; a = a * sA + b * sB; m = M;
  };
  merge(m0, d0, x0, m1, d1, x1);
  merge(m2, d2, x2, m3, d3, x3);
  merge(m0, d0, x0, m2, d2, x2);

  if (lane < 32) {
    float o = x0 / (d0 + 1e-16f) + qkvs2[(size_t)n * 128 + 96 + c];
    outp[(size_t)n * 32 + c] = fmaxf(o, 0.f);
  }
}

// ---------------- launcher ----------------
extern "C" void kernel_launch(void* const* d_in, const int* in_sizes, int n_in,
                              void* d_out, int out_size, void* d_ws, size_t ws_size,
                              hipStream_t stream) {
  const float* x   = (const float*)d_in[0];
  const float* lu  = (const float*)d_in[1];
  const int*   ei  = (const int*)d_in[2];
  const float* tt  = (const float*)d_in[3];
  const float* msg = (const float*)d_in[4];
  const float* tw  = (const float*)d_in[5];
  const float* tb  = (const float*)d_in[6];
  const float* Wq1 = (const float*)d_in[7];  const float* bq1 = (const float*)d_in[8];
  const float* Wk1 = (const float*)d_in[9];  const float* bk1 = (const float*)d_in[10];
  const float* Wv1 = (const float*)d_in[11]; const float* bv1 = (const float*)d_in[12];
  const float* We1 = (const float*)d_in[13];
  const float* Ws1 = (const float*)d_in[14]; const float* bs1 = (const float*)d_in[15];
  const float* Wq2 = (const float*)d_in[16]; const float* bq2 = (const float*)d_in[17];
  const float* Wk2 = (const float*)d_in[18]; const float* bk2 = (const float*)d_in[19];
  const float* Wv2 = (const float*)d_in[20]; const float* bv2 = (const float*)d_in[21];
  const float* We2 = (const float*)d_in[22];
  const float* Ws2 = (const float*)d_in[23]; const float* bs2 = (const float*)d_in[24];

  const int* srcp = ei;
  const int* dstp = ei + N_EDGES;

  char* p = (char*)d_ws;
  auto alloc = [&](size_t bytes) -> char* {
    char* r = p;
    p += (bytes + 255) & ~(size_t)255;
    return r;
  };
  int*   deg     = (int*)alloc((size_t)N_NODES * 4);
  int*   fill    = (int*)alloc((size_t)N_NODES * 4);
  int*   rowptr  = (int*)alloc((size_t)(N_NODES + 1) * 4);
  int*   srcs    = (int*)alloc((size_t)N_EDGES * 4);
  int*   dsts    = (int*)alloc((size_t)N_EDGES * 4);
  int*   eidA    = (int*)alloc((size_t)N_EDGES * 4);
  float* rel_s   = (float*)alloc((size_t)N_EDGES * 4);
  unsigned short* xa   = (unsigned short*)alloc((size_t)RT1 * 32768);
  unsigned short* W1f  = (unsigned short*)alloc((size_t)8 * 64 * 1024);
  unsigned short* We1f = (unsigned short*)alloc((size_t)8 * 16 * 1024);
  unsigned short* W2f  = (unsigned short*)alloc((size_t)8 * 8 * 1024);
  unsigned short* We2f = (unsigned short*)alloc((size_t)8 * 4 * 1024);
  float* bcat1  = (float*)alloc(1024 * 4);
  float* bcat2  = (float*)alloc(128 * 4);
  float* qf     = (float*)alloc((size_t)N_NODES * 256 * 4);
  unsigned short* kvb = (unsigned short*)alloc((size_t)N_NODES * 512 * 2);
  float* sf     = (float*)alloc((size_t)N_NODES * 256 * 4);
  char*  segrec = (char*)alloc((size_t)N_NODES * MAXSEG * SEGSTRIDE);   // 92 MB
  float* qkvs2  = (float*)alloc((size_t)N_NODES * 128 * 4);
  unsigned short* e2b = (unsigned short*)alloc((size_t)N_EDGES * 32 * 2);
  float* outp   = (float*)d_out;

  hipMemsetAsync(deg, 0, (size_t)N_NODES * 4, stream);
  hipMemsetAsync(fill, 0, (size_t)N_NODES * 4, stream);

  count_kernel<<<625, 256, 0, stream>>>(dstp, deg, N_EDGES);
  scan_kernel<<<1, 1024, 0, stream>>>(deg, rowptr, N_NODES);
  scatter_kernel<<<625, 256, 0, stream>>>(lu, tt, srcp, dstp, rowptr, fill,
                                          srcs, dsts, eidA, rel_s, N_EDGES);

  conv_all_kernel<<<ceildiv(CONVX_T + 369792, 256), 256, 0, stream>>>(
      x, xa, Wq1, Wk1, Wv1, Ws1, We1, Wq2, Wk2, Wv2, Ws2, We2,
      bq1, bk1, bv1, bs1, bq2, bk2, bv2, bs2,
      W1f, We1f, W2f, We2f, bcat1, bcat2);

  // node1 FIRST (edge_fused consumes qf/kvb — kernel boundary = synchronization)
  node1_gemm<<<RT1 * 4, 512, 0, stream>>>(xa, W1f, bcat1, qf, kvb, sf);

  // edge GEMM + fused layer-1 attention (split prologue, in-wave epilogue)
  edge_fused<<<RTE, 512, 0, stream>>>(
      qf, kvb, We1f, We2f, segrec, e2b,
      rel_s, tw, tb, msg, eidA, srcs, dsts, rowptr);

  // merge + layer-2 node GEMM fused
  node2_fused<<<RT1, 256, 0, stream>>>(segrec, rowptr, sf, W2f, bcat2, qkvs2);
  attn2_kernel<<<ceildiv(N_NODES, 4), 256, 0, stream>>>(qkvs2, e2b, srcs, rowptr, outp);
}

// Round 16
// 164.540 us; speedup vs baseline: 1.0468x; 1.0468x over previous
//
#include <hip/hip_runtime.h>
#include <math.h>

#define N_NODES 10000
#define N_EDGES 160000
#define RT1 157      // ceil(10000/64)
#define RTE 2500     // 160000/64
#define CONVX_T (RT1 * 64 * 32)   // 321536
#define MAXSEG 16
#define SEGSTRIDE 576             // bytes: 512 pacc(bf16x256) + 32 m(f32x8) + 32 den(f32x8)

static inline int ceildiv(int a, int b) { return (a + b - 1) / b; }

typedef float f32x4 __attribute__((ext_vector_type(4)));
typedef short bf16x8 __attribute__((ext_vector_type(8)));

__device__ __forceinline__ unsigned short f2bf(float f) {
  unsigned int u = __builtin_bit_cast(unsigned int, f);
  u += 0x7FFFu + ((u >> 16) & 1u);   // RNE
  return (unsigned short)(u >> 16);
}
__device__ __forceinline__ float bf2f(unsigned short h) {
  unsigned int u = ((unsigned int)h) << 16;
  return __builtin_bit_cast(float, u);
}

// ---------------- prep ----------------
__global__ void count_kernel(const int* __restrict__ dstp, int* __restrict__ deg, int E) {
  for (int i = blockIdx.x * blockDim.x + threadIdx.x; i < E; i += gridDim.x * blockDim.x)
    atomicAdd(&deg[dstp[i]], 1);
}

__global__ void scan_kernel(const int* __restrict__ deg, int* __restrict__ rowptr, int n) {
  __shared__ int part[1024];
  const int tid = threadIdx.x;
  const int CHK = 10;
  int base = tid * CHK;
  int loc[CHK];
  int s = 0;
#pragma unroll
  for (int j = 0; j < CHK; ++j) {
    int idx = base + j;
    int v = (idx < n) ? deg[idx] : 0;
    loc[j] = s; s += v;
  }
  part[tid] = s;
  __syncthreads();
  for (int off = 1; off < 1024; off <<= 1) {
    int y = (tid >= off) ? part[tid - off] : 0;
    __syncthreads();
    part[tid] += y;
    __syncthreads();
  }
  int pre = tid ? part[tid - 1] : 0;
#pragma unroll
  for (int j = 0; j < CHK; ++j) {
    int idx = base + j;
    if (idx < n) rowptr[idx] = pre + loc[j];
  }
  if (tid == 1023) rowptr[n] = part[1023];
}

// sorted-order side arrays: srcs, dsts, eid, rel_s
__global__ void scatter_kernel(const float* __restrict__ lu, const float* __restrict__ tt,
                               const int* __restrict__ srcp, const int* __restrict__ dstp,
                               const int* __restrict__ rowptr, int* __restrict__ fill,
                               int* __restrict__ srcs, int* __restrict__ dsts,
                               int* __restrict__ eidA, float* __restrict__ rel_s, int E) {
  for (int e = blockIdx.x * blockDim.x + threadIdx.x; e < E; e += gridDim.x * blockDim.x) {
    int d = dstp[e], s = srcp[e];
    int pos = atomicAdd(&fill[d], 1);
    int slot = rowptr[d] + pos;
    srcs[slot] = s;
    dsts[slot] = d;
    eidA[slot] = e;
    rel_s[slot] = lu[s] - tt[e];
  }
}

// ---------------- all format conversions in ONE launch ----------------
__device__ __forceinline__ void wstore(const float* __restrict__ W, unsigned short* __restrict__ out,
                                       int Nin, int n_off, int NFtot, int k, int c) {
  int gc = n_off + c;
  int ks=k>>5, kg=(k>>3)&3, j=k&7, nf=gc>>4, ic=gc&15;
  out[(size_t)(ks*NFtot+nf)*512 + (ic+16*kg)*8 + j] = f2bf(W[(size_t)k*Nin + c]);
}

__global__ void conv_all_kernel(const float* __restrict__ x, unsigned short* __restrict__ xa,
                                const float* Wq1, const float* Wk1, const float* Wv1, const float* Ws1,
                                const float* We1, const float* Wq2, const float* Wk2, const float* Wv2,
                                const float* Ws2, const float* We2,
                                const float* bq1, const float* bk1, const float* bv1, const float* bs1,
                                const float* bq2, const float* bk2, const float* bv2, const float* bs2,
                                unsigned short* W1f, unsigned short* We1f, unsigned short* W2f,
                                unsigned short* We2f, float* bcat1, float* bcat2) {
  int t0 = blockIdx.x * blockDim.x + threadIdx.x;
  if (t0 < CONVX_T) {
    int i = t0 >> 5, k8 = t0 & 31;
    union { uint4 q; unsigned short s[8]; } u;
    if (i < N_NODES) {
      const float4* px = (const float4*)(x + (size_t)i * 256 + k8 * 8);
      float4 f0 = px[0], f1 = px[1];
      u.s[0]=f2bf(f0.x); u.s[1]=f2bf(f0.y); u.s[2]=f2bf(f0.z); u.s[3]=f2bf(f0.w);
      u.s[4]=f2bf(f1.x); u.s[5]=f2bf(f1.y); u.s[6]=f2bf(f1.z); u.s[7]=f2bf(f1.w);
    } else {
      u.q = make_uint4(0,0,0,0);
    }
    int rt=i>>6, rf=(i>>4)&3, ir=i&15, ks=k8>>2, kg=k8&3;
    *(uint4*)&xa[(size_t)rt*16384 + ks*2048 + rf*512 + (ir+16*kg)*8] = u.q;
    return;
  }
  int t = t0 - CONVX_T;
  if (t < 262144) {               // W1f: 4 x 256x256
    int w = t >> 16, r = t & 65535, k = r >> 8, c = r & 255;
    const float* W = (w == 0) ? Wq1 : (w == 1) ? Wk1 : (w == 2) ? Wv1 : Ws1;
    wstore(W, W1f, 256, w * 256, 64, k, c);
  } else if (t < 327680) {        // We1f: 256x256
    int r = t - 262144, k = r >> 8, c = r & 255;
    wstore(We1, We1f, 256, 0, 16, k, c);
  } else if (t < 360448) {        // W2f: 4 x 256x32
    int r = t - 327680, w = r >> 13, r2 = r & 8191, k = r2 >> 5, c = r2 & 31;
    const float* W = (w == 0) ? Wq2 : (w == 1) ? Wk2 : (w == 2) ? Wv2 : Ws2;
    wstore(W, W2f, 32, w * 32, 8, k, c);
  } else if (t < 368640) {        // We2f: 256x32 (cols 32-63 pre-zeroed by memset)
    int r = t - 360448, k = r >> 5, c = r & 31;
    wstore(We2, We2f, 32, 0, 4, k, c);
  } else if (t < 369792) {        // biases
    int r = t - 368640;
    if (r < 1024) {
      const float* b = (r < 256) ? bq1 : (r < 512) ? bk1 : (r < 768) ? bv1 : bs1;
      bcat1[r] = b[r & 255];
    } else {
      int r2 = r - 1024;
      const float* b = (r2 < 32) ? bq2 : (r2 < 64) ? bk2 : (r2 < 96) ? bv2 : bs2;
      bcat2[r2] = b[r2 & 31];
    }
  }
}

// ---------------- node1 GEMM (SEPARATE launch — edge_fused consumes qf/kvb) ----------------
__global__ __launch_bounds__(512, 4)
void node1_gemm(const unsigned short* __restrict__ xa, const unsigned short* __restrict__ W1f,
                const float* __restrict__ bcat1, float* __restrict__ qf,
                unsigned short* __restrict__ kvb, float* __restrict__ sf) {
  __shared__ char ldsraw[32768];
  uint4* lds4 = (uint4*)ldsraw;
  const int tid = threadIdx.x;
  const int wid = tid >> 6, lane = tid & 63;
  const int fr0 = (lane >> 4) * 4;
  const int fc0 = lane & 15;
  const int rt0 = blockIdx.x % RT1;
  const int y = blockIdx.x / RT1;              // 0..3: q | k | v | s
  const int phase = rt0 & 7;

#pragma unroll
  for (int s = 0; s < 4; ++s)
    lds4[tid + s * 512] = *(const uint4*)(xa + (size_t)rt0 * 16384 + (size_t)(tid + s * 512) * 8);
  __syncthreads();

  f32x4 acc[4][2];
#pragma unroll
  for (int i = 0; i < 4; ++i)
#pragma unroll
    for (int j = 0; j < 2; ++j) acc[i][j] = (f32x4){0.f, 0.f, 0.f, 0.f};

  bf16x8 aN0, aN1, aN2, aN3, bN0, bN1;
  {
    const int ks = phase;
    aN0 = *(const bf16x8*)&lds4[ks * 256 + 0 * 64 + lane];
    aN1 = *(const bf16x8*)&lds4[ks * 256 + 1 * 64 + lane];
    aN2 = *(const bf16x8*)&lds4[ks * 256 + 2 * 64 + lane];
    aN3 = *(const bf16x8*)&lds4[ks * 256 + 3 * 64 + lane];
    bN0 = *(const bf16x8*)(W1f + ((size_t)(ks * 64 + y * 16 + wid * 2 + 0)) * 512 + (size_t)lane * 8);
    bN1 = *(const bf16x8*)(W1f + ((size_t)(ks * 64 + y * 16 + wid * 2 + 1)) * 512 + (size_t)lane * 8);
  }
#pragma unroll
  for (int ksi = 0; ksi < 8; ++ksi) {
    bf16x8 aC0 = aN0, aC1 = aN1, aC2 = aN2, aC3 = aN3;
    bf16x8 bC0 = bN0, bC1 = bN1;
    if (ksi < 7) {
      const int ks2 = (ksi + 1) ^ phase;
      aN0 = *(const bf16x8*)&lds4[ks2 * 256 + 0 * 64 + lane];
      aN1 = *(const bf16x8*)&lds4[ks2 * 256 + 1 * 64 + lane];
      aN2 = *(const bf16x8*)&lds4[ks2 * 256 + 2 * 64 + lane];
      aN3 = *(const bf16x8*)&lds4[ks2 * 256 + 3 * 64 + lane];
      bN0 = *(const bf16x8*)(W1f + ((size_t)(ks2 * 64 + y * 16 + wid * 2 + 0)) * 512 + (size_t)lane * 8);
      bN1 = *(const bf16x8*)(W1f + ((size_t)(ks2 * 64 + y * 16 + wid * 2 + 1)) * 512 + (size_t)lane * 8);
    }
    acc[0][0] = __builtin_amdgcn_mfma_f32_16x16x32_bf16(aC0, bC0, acc[0][0], 0, 0, 0);
    acc[1][0] = __builtin_amdgcn_mfma_f32_16x16x32_bf16(aC1, bC0, acc[1][0], 0, 0, 0);
    acc[2][0] = __builtin_amdgcn_mfma_f32_16x16x32_bf16(aC2, bC0, acc[2][0], 0, 0, 0);
    acc[3][0] = __builtin_amdgcn_mfma_f32_16x16x32_bf16(aC3, bC0, acc[3][0], 0, 0, 0);
    acc[0][1] = __builtin_amdgcn_mfma_f32_16x16x32_bf16(aC0, bC1, acc[0][1], 0, 0, 0);
    acc[1][1] = __builtin_amdgcn_mfma_f32_16x16x32_bf16(aC1, bC1, acc[1][1], 0, 0, 0);
    acc[2][1] = __builtin_amdgcn_mfma_f32_16x16x32_bf16(aC2, bC1, acc[2][1], 0, 0, 0);
    acc[3][1] = __builtin_amdgcn_mfma_f32_16x16x32_bf16(aC3, bC1, acc[3][1], 0, 0, 0);
  }

  bool bf16path;
  void* dstp_; int cstr_, dc0_, bcol0_;
  if (y == 0)      { bf16path = false; dstp_ = qf;  cstr_ = 256; dc0_ = 0;   bcol0_ = 0; }
  else if (y == 1) { bf16path = true;  dstp_ = kvb; cstr_ = 512; dc0_ = 0;   bcol0_ = 256; }
  else if (y == 2) { bf16path = true;  dstp_ = kvb; cstr_ = 512; dc0_ = 256; bcol0_ = 512; }
  else             { bf16path = false; dstp_ = sf;  cstr_ = 256; dc0_ = 0;   bcol0_ = 768; }
  if (!bf16path) {
    float* dst = (float*)dstp_;
    const int row0 = rt0 * 64 + fr0;
#pragma unroll
    for (int cf = 0; cf < 2; ++cf) {
      int c = wid * 32 + cf * 16 + fc0;
      float bv = bcat1[bcol0_ + c];
#pragma unroll
      for (int rf = 0; rf < 4; ++rf) {
#pragma unroll
        for (int j = 0; j < 4; ++j) {
          int r = row0 + rf * 16 + j;
          if (r < N_NODES) dst[(size_t)r * cstr_ + c] = acc[rf][cf][j] + bv;
        }
      }
    }
  } else {
    __syncthreads();
    unsigned short* cl = (unsigned short*)ldsraw;   // [64][72]
    unsigned short* dst = (unsigned short*)dstp_;
    for (int pass = 0; pass < 4; ++pass) {
      if ((wid >> 1) == pass) {
#pragma unroll
        for (int cf = 0; cf < 2; ++cf) {
          int c = (wid & 1) * 32 + cf * 16 + fc0;
          float bv = bcat1[bcol0_ + pass * 64 + c];
#pragma unroll
          for (int rf = 0; rf < 4; ++rf)
#pragma unroll
            for (int j = 0; j < 4; ++j)
              cl[(fr0 + rf * 16 + j) * 72 + c] = f2bf(acc[rf][cf][j] + bv);
        }
      }
      __syncthreads();
      {
        int row = tid >> 3, cc = (tid & 7) * 8;
        int gr = rt0 * 64 + row;
        if (gr < N_NODES)
          *(uint4*)&dst[(size_t)gr * cstr_ + dc0_ + pass * 64 + cc] = *(const uint4*)&cl[row * 72 + cc];
      }
      __syncthreads();
    }
  }
}

// ---------------- edge GEMM + FUSED layer-1 attention (R14 core + q-dedup) ----------------
__global__ __launch_bounds__(512, 4)
void edge_fused(const float* __restrict__ qf, const unsigned short* __restrict__ kvb,
                const unsigned short* __restrict__ We1f, const unsigned short* __restrict__ We2f,
                char* __restrict__ segrec, unsigned short* __restrict__ e2b,
                const float* __restrict__ rel_s, const float* __restrict__ tw,
                const float* __restrict__ tb, const float* __restrict__ msg,
                const int* __restrict__ eidA, const int* __restrict__ srcsA,
                const int* __restrict__ dstsA, const int* __restrict__ rowptr) {
  __shared__ char ldsraw[38912];
  uint4* lds4 = (uint4*)ldsraw;                               // K-loop A tile (32KB)
  unsigned short* e1t = (unsigned short*)ldsraw;              // [64][260] epilogue
  int* dseg     = (int*)(ldsraw + 33280);                     // [64]
  int* sseg     = (int*)(ldsraw + 33536);                     // [64]
  unsigned short* cl2 = (unsigned short*)(ldsraw + 33792);    // [64][40]

  const int tid = threadIdx.x;
  const int wid = tid >> 6, lane = tid & 63;
  const int bx = blockIdx.x;
  const int fr0 = (lane >> 4) * 4;
  const int fc0 = lane & 15;
  const int rt0 = bx;
  const int phase = bx & 7;

  // prologue: synth A (cos | gathered msg) into LDS; ONE barrier (R14)
  {
    const int rem = tid & 255;
    const int ksh = tid >> 8;                // 0 or 1
    const int arf = rem >> 6, ar2 = rem & 63, air = ar2 & 15, akg = ar2 >> 4;
    const int slot = rt0 * 64 + arf * 16 + air;
    float rl = rel_s[slot];
    int eorg = eidA[slot];
    if (tid < 64) {
      dseg[tid] = dstsA[rt0 * 64 + tid];
      sseg[tid] = srcsA[rt0 * 64 + tid];
    }
#pragma unroll
    for (int s = 0; s < 2; ++s) {
      int ks = ksh + s * 2;                  // cos K-steps 0..3
      int k8 = ks * 4 + akg;
      const float4* twp = (const float4*)(tw + k8 * 8);
      const float4* tbp = (const float4*)(tb + k8 * 8);
      float4 w0 = twp[0], w1 = twp[1], b0 = tbp[0], b1 = tbp[1];
      union { uint4 q; unsigned short us[8]; } u;
      u.us[0]=f2bf(__cosf(rl*w0.x+b0.x)); u.us[1]=f2bf(__cosf(rl*w0.y+b0.y));
      u.us[2]=f2bf(__cosf(rl*w0.z+b0.z)); u.us[3]=f2bf(__cosf(rl*w0.w+b0.w));
      u.us[4]=f2bf(__cosf(rl*w1.x+b1.x)); u.us[5]=f2bf(__cosf(rl*w1.y+b1.y));
      u.us[6]=f2bf(__cosf(rl*w1.z+b1.z)); u.us[7]=f2bf(__cosf(rl*w1.w+b1.w));
      lds4[ks * 256 + rem] = u.q;
    }
#pragma unroll
    for (int s = 0; s < 2; ++s) {
      int ks = 4 + ksh + s * 2;              // msg K-steps 4..7
      int k8 = ks * 4 + akg;                 // 16..31
      const float4* pm = (const float4*)(msg + (size_t)eorg * 128 + (size_t)(k8 - 16) * 8);
      float4 f0 = pm[0], f1 = pm[1];
      union { uint4 q; unsigned short us[8]; } u;
      u.us[0]=f2bf(f0.x); u.us[1]=f2bf(f0.y); u.us[2]=f2bf(f0.z); u.us[3]=f2bf(f0.w);
      u.us[4]=f2bf(f1.x); u.us[5]=f2bf(f1.y); u.us[6]=f2bf(f1.z); u.us[7]=f2bf(f1.w);
      lds4[ks * 256 + rem] = u.q;
    }
  }
  __syncthreads();

  f32x4 acc[4][2];
  f32x4 acc2[4];
#pragma unroll
  for (int i = 0; i < 4; ++i) {
    acc2[i] = (f32x4){0.f, 0.f, 0.f, 0.f};
#pragma unroll
    for (int j = 0; j < 2; ++j) acc[i][j] = (f32x4){0.f, 0.f, 0.f, 0.f};
  }

  // K-loop: 1-step software pipeline (R14)
  bf16x8 aN0, aN1, aN2, aN3, bN0, bN1, b2N;
  {
    const int ks = phase;
    aN0 = *(const bf16x8*)&lds4[ks * 256 + 0 * 64 + lane];
    aN1 = *(const bf16x8*)&lds4[ks * 256 + 1 * 64 + lane];
    aN2 = *(const bf16x8*)&lds4[ks * 256 + 2 * 64 + lane];
    aN3 = *(const bf16x8*)&lds4[ks * 256 + 3 * 64 + lane];
    bN0 = *(const bf16x8*)(We1f + ((size_t)(ks * 16 + wid * 2 + 0)) * 512 + (size_t)lane * 8);
    bN1 = *(const bf16x8*)(We1f + ((size_t)(ks * 16 + wid * 2 + 1)) * 512 + (size_t)lane * 8);
    b2N = 0;
    if (wid < 2) b2N = *(const bf16x8*)(We2f + ((size_t)(ks * 4 + wid)) * 512 + (size_t)lane * 8);
  }
#pragma unroll
  for (int ksi = 0; ksi < 8; ++ksi) {
    bf16x8 aC0 = aN0, aC1 = aN1, aC2 = aN2, aC3 = aN3;
    bf16x8 bC0 = bN0, bC1 = bN1, b2C = b2N;
    if (ksi < 7) {
      const int ks2 = (ksi + 1) ^ phase;
      aN0 = *(const bf16x8*)&lds4[ks2 * 256 + 0 * 64 + lane];
      aN1 = *(const bf16x8*)&lds4[ks2 * 256 + 1 * 64 + lane];
      aN2 = *(const bf16x8*)&lds4[ks2 * 256 + 2 * 64 + lane];
      aN3 = *(const bf16x8*)&lds4[ks2 * 256 + 3 * 64 + lane];
      bN0 = *(const bf16x8*)(We1f + ((size_t)(ks2 * 16 + wid * 2 + 0)) * 512 + (size_t)lane * 8);
      bN1 = *(const bf16x8*)(We1f + ((size_t)(ks2 * 16 + wid * 2 + 1)) * 512 + (size_t)lane * 8);
      if (wid < 2) b2N = *(const bf16x8*)(We2f + ((size_t)(ks2 * 4 + wid)) * 512 + (size_t)lane * 8);
    }
    acc[0][0] = __builtin_amdgcn_mfma_f32_16x16x32_bf16(aC0, bC0, acc[0][0], 0, 0, 0);
    acc[1][0] = __builtin_amdgcn_mfma_f32_16x16x32_bf16(aC1, bC0, acc[1][0], 0, 0, 0);
    acc[2][0] = __builtin_amdgcn_mfma_f32_16x16x32_bf16(aC2, bC0, acc[2][0], 0, 0, 0);
    acc[3][0] = __builtin_amdgcn_mfma_f32_16x16x32_bf16(aC3, bC0, acc[3][0], 0, 0, 0);
    acc[0][1] = __builtin_amdgcn_mfma_f32_16x16x32_bf16(aC0, bC1, acc[0][1], 0, 0, 0);
    acc[1][1] = __builtin_amdgcn_mfma_f32_16x16x32_bf16(aC1, bC1, acc[1][1], 0, 0, 0);
    acc[2][1] = __builtin_amdgcn_mfma_f32_16x16x32_bf16(aC2, bC1, acc[2][1], 0, 0, 0);
    acc[3][1] = __builtin_amdgcn_mfma_f32_16x16x32_bf16(aC3, bC1, acc[3][1], 0, 0, 0);
    if (wid < 2) {
      acc2[0] = __builtin_amdgcn_mfma_f32_16x16x32_bf16(aC0, b2C, acc2[0], 0, 0, 0);
      acc2[1] = __builtin_amdgcn_mfma_f32_16x16x32_bf16(aC1, b2C, acc2[1], 0, 0, 0);
      acc2[2] = __builtin_amdgcn_mfma_f32_16x16x32_bf16(aC2, b2C, acc2[2], 0, 0, 0);
      acc2[3] = __builtin_amdgcn_mfma_f32_16x16x32_bf16(aC3, b2C, acc2[3], 0, 0, 0);
    }
  }

  // ---- epilogue: dump e1/e2, ONE barrier, then all in-wave ----
  __syncthreads();   // A-tile reads done; reuse LDS
#pragma unroll
  for (int cf = 0; cf < 2; ++cf)
#pragma unroll
    for (int rf = 0; rf < 4; ++rf)
#pragma unroll
      for (int j = 0; j < 4; ++j)
        e1t[(fr0 + rf * 16 + j) * 260 + wid * 32 + cf * 16 + fc0] = f2bf(acc[rf][cf][j]);
  if (wid < 2) {
#pragma unroll
    for (int rf = 0; rf < 4; ++rf)
#pragma unroll
      for (int j = 0; j < 4; ++j)
        cl2[(fr0 + rf * 16 + j) * 40 + wid * 16 + fc0] = f2bf(acc2[rf][j]);
  }
  __syncthreads();

  // e2b store first (independent, writes in flight early)
  if (tid < 256) {
    int row = tid >> 2, cc = (tid & 3) * 8;
    *(uint4*)&e2b[(size_t)(rt0 * 64 + row) * 32 + cc] = *(const uint4*)&cl2[row * 40 + cc];
  }

  // ---- in-wave fused attention: wave wid owns rows [wid*8, wid*8+8) ----
  {
    const int base = wid * 8;
    const int rgj = bx * 8 + wid;
    int d8[8], s8[8];
#pragma unroll
    for (int t = 0; t < 8; ++t) { d8[t] = dseg[base + t]; s8[t] = sseg[base + t]; }

    // batched gathers: k (bf16x4) + e (LDS); q DEDUPED (sorted dst runs,
    // wave-uniform branch — typically 1-2 distinct dsts per 8 rows)
    ushort4 k8[8], e8[8];
#pragma unroll
    for (int t = 0; t < 8; ++t) {
      k8[t] = *(const ushort4*)&kvb[(size_t)s8[t] * 512 + lane * 4];
      e8[t] = *(const ushort4*)&e1t[(base + t) * 260 + lane * 4];
    }
    float4 q8[8];
    q8[0] = *(const float4*)&qf[(size_t)d8[0] * 256 + lane * 4];
#pragma unroll
    for (int t = 1; t < 8; ++t) {
      if (d8[t] == d8[t - 1]) q8[t] = q8[t - 1];
      else q8[t] = *(const float4*)&qf[(size_t)d8[t] * 256 + lane * 4];
    }
    // scores (8-lane shfl reduce; each 8-lane group = one head)
    float sc[8];
#pragma unroll
    for (int t = 0; t < 8; ++t) {
      float p = q8[t].x * (bf2f(k8[t].x) + bf2f(e8[t].x))
              + q8[t].y * (bf2f(k8[t].y) + bf2f(e8[t].y))
              + q8[t].z * (bf2f(k8[t].z) + bf2f(e8[t].z))
              + q8[t].w * (bf2f(k8[t].w) + bf2f(e8[t].w));
      p += __shfl_xor(p, 1); p += __shfl_xor(p, 2); p += __shfl_xor(p, 4);
      sc[t] = p * 0.17677669529663687f;
    }
    // issue v gathers now (latency hides under softmax VALU below)
    ushort4 v8[8];
#pragma unroll
    for (int t = 0; t < 8; ++t)
      v8[t] = *(const ushort4*)&kvb[(size_t)s8[t] * 512 + 256 + lane * 4];

    // segmented softmax over t in registers (runs contiguous in t)
    float m8[8], w8[8];
#pragma unroll
    for (int t = 0; t < 8; ++t) {
      float mm = sc[t];
#pragma unroll
      for (int u = 0; u < 8; ++u)
        if (d8[u] == d8[t]) mm = fmaxf(mm, sc[u]);
      m8[t] = mm;
      w8[t] = __expf(sc[t] - mm);
    }
#pragma unroll
    for (int t = 0; t < 8; ++t) {
      bool first = (t == 0) || (d8[t - 1] != d8[t]);
      if (first && (lane & 7) == 0) {
        float den = 0.f;
#pragma unroll
        for (int u = 0; u < 8; ++u)
          if (d8[u] == d8[t]) den += w8[u];
        int j = rgj - (rowptr[d8[t]] >> 3);
        if (j < MAXSEG) {
          float* rec = (float*)(segrec + ((size_t)d8[t] * MAXSEG + j) * SEGSTRIDE);
          rec[128 + (lane >> 3)] = m8[t];
          rec[136 + (lane >> 3)] = den;
        }
      }
    }
    f32x4 pacc = (f32x4){0.f, 0.f, 0.f, 0.f};
    int cur = d8[0];
#pragma unroll
    for (int t = 0; t < 8; ++t) {
      if (d8[t] != cur) {
        int j = rgj - (rowptr[cur] >> 3);
        if (j < MAXSEG) {
          unsigned short* pp = (unsigned short*)(segrec + ((size_t)cur * MAXSEG + j) * SEGSTRIDE);
          ushort4 o;
          o.x = f2bf(pacc[0]); o.y = f2bf(pacc[1]); o.z = f2bf(pacc[2]); o.w = f2bf(pacc[3]);
          *(ushort4*)&pp[lane * 4] = o;
        }
        pacc = (f32x4){0.f, 0.f, 0.f, 0.f};
        cur = d8[t];
      }
      pacc[0] += w8[t] * (bf2f(v8[t].x) + bf2f(e8[t].x));
      pacc[1] += w8[t] * (bf2f(v8[t].y) + bf2f(e8[t].y));
      pacc[2] += w8[t] * (bf2f(v8[t].z) + bf2f(e8[t].z));
      pacc[3] += w8[t] * (bf2f(v8[t].w) + bf2f(e8[t].w));
    }
    {
      int j = rgj - (rowptr[cur] >> 3);
      if (j < MAXSEG) {
        unsigned short* pp = (unsigned short*)(segrec + ((size_t)cur * MAXSEG + j) * SEGSTRIDE);
        ushort4 o;
        o.x = f2bf(pacc[0]); o.y = f2bf(pacc[1]); o.z = f2bf(pacc[2]); o.w = f2bf(pacc[3]);
        *(ushort4*)&pp[lane * 4] = o;
      }
    }
  }
}

// ---------------- node2 fused: merge segments -> h (LDS frag tile) -> GEMM ----------------
__global__ __launch_bounds__(256)
void node2_fused(const char* __restrict__ segrec, const int* __restrict__ rowptr,
                 const float* __restrict__ sf, const unsigned short* __restrict__ W2f,
                 const float* __restrict__ bcat2, float* __restrict__ qkvs2) {
  __shared__ unsigned short haL[8 * 2048];   // 32KB frag tile
  const int tid = threadIdx.x;
  const int wid = tid >> 6, lane = tid & 63;
  const int rt0 = blockIdx.x;

  {
    const int nl = tid >> 2;
    const int n = rt0 * 64 + nl;
    const int cb = (tid & 3) * 64;
    const int rf = (nl >> 4) & 3, ir = nl & 15;
    if (n < N_NODES) {
      const int beg = rowptr[n], end = rowptr[n + 1];
      int span = 0;
      if (beg < end) {
        span = ((end - 1) >> 3) - (beg >> 3) + 1;
        if (span > MAXSEG) span = MAXSEG;
      }
#pragma unroll
      for (int cc = 0; cc < 4; ++cc) {
        const int c0 = cb + cc * 16;
        const int h = c0 >> 5;
        float o[16];
        if (span == 0) {
#pragma unroll
          for (int q = 0; q < 16; ++q) o[q] = 0.f;
        } else {
          float M = -INFINITY;
          for (int j = 0; j < span; ++j) {
            const float* rec = (const float*)(segrec + ((size_t)n * MAXSEG + j) * SEGSTRIDE);
            M = fmaxf(M, rec[128 + h]);
          }
          float den = 0.f;
#pragma unroll
          for (int q = 0; q < 16; ++q) o[q] = 0.f;
          for (int j = 0; j < span; ++j) {
            const float* rec = (const float*)(segrec + ((size_t)n * MAXSEG + j) * SEGSTRIDE);
            float scj = __expf(rec[128 + h] - M);
            den += scj * rec[136 + h];
            const unsigned short* pp = (const unsigned short*)rec;
#pragma unroll
            for (int q4 = 0; q4 < 4; ++q4) {
              ushort4 p4 = *(const ushort4*)&pp[c0 + q4 * 4];
              o[q4*4+0] += scj * bf2f(p4.x); o[q4*4+1] += scj * bf2f(p4.y);
              o[q4*4+2] += scj * bf2f(p4.z); o[q4*4+3] += scj * bf2f(p4.w);
            }
          }
          const float inv = 1.f / (den + 1e-16f);
#pragma unroll
          for (int q = 0; q < 16; ++q) o[q] *= inv;
        }
#pragma unroll
        for (int q4 = 0; q4 < 4; ++q4) {
          const int c = c0 + q4 * 4;
          float4 sk = *(const float4*)&sf[(size_t)n * 256 + c];
          ushort4 w4;
          w4.x = f2bf(fmaxf(o[q4*4+0] + sk.x, 0.f));
          w4.y = f2bf(fmaxf(o[q4*4+1] + sk.y, 0.f));
          w4.z = f2bf(fmaxf(o[q4*4+2] + sk.z, 0.f));
          w4.w = f2bf(fmaxf(o[q4*4+3] + sk.w, 0.f));
          int ks = c >> 5, kg = (c >> 3) & 3, j = c & 7;
          *(ushort4*)&haL[ks * 2048 + rf * 512 + (ir + 16 * kg) * 8 + j] = w4;
        }
      }
    } else {
#pragma unroll
      for (int cc = 0; cc < 4; ++cc) {
        const int c0 = cb + cc * 16;
#pragma unroll
        for (int q4 = 0; q4 < 4; ++q4) {
          const int c = c0 + q4 * 4;
          int ks = c >> 5, kg = (c >> 3) & 3, j = c & 7;
          ushort4 z; z.x = z.y = z.z = z.w = 0;
          *(ushort4*)&haL[ks * 2048 + rf * 512 + (ir + 16 * kg) * 8 + j] = z;
        }
      }
    }
  }
  __syncthreads();

  f32x4 acc[4][2];
#pragma unroll
  for (int i = 0; i < 4; ++i)
#pragma unroll
    for (int j = 0; j < 2; ++j) acc[i][j] = (f32x4){0.f, 0.f, 0.f, 0.f};

#pragma unroll
  for (int ks = 0; ks < 8; ++ks) {
    bf16x8 a[4], b[2];
#pragma unroll
    for (int rf = 0; rf < 4; ++rf)
      a[rf] = *(const bf16x8*)&haL[ks * 2048 + (rf * 64 + lane) * 8];
#pragma unroll
    for (int cf = 0; cf < 2; ++cf)
      b[cf] = *(const bf16x8*)(W2f + ((size_t)(ks * 8 + wid * 2 + cf)) * 512 + (size_t)lane * 8);
#pragma unroll
    for (int rf = 0; rf < 4; ++rf)
#pragma unroll
      for (int cf = 0; cf < 2; ++cf)
        acc[rf][cf] = __builtin_amdgcn_mfma_f32_16x16x32_bf16(a[rf], b[cf], acc[rf][cf], 0, 0, 0);
  }

  const int row0 = rt0 * 64 + ((lane >> 4) * 4);
  const int cb2 = wid * 32 + (lane & 15);
#pragma unroll
  for (int cf = 0; cf < 2; ++cf) {
    int c = cb2 + cf * 16;
    float bv = bcat2[c];
#pragma unroll
    for (int rf = 0; rf < 4; ++rf) {
#pragma unroll
      for (int j = 0; j < 4; ++j) {
        int r = row0 + rf * 16 + j;
        if (r < N_NODES) qkvs2[(size_t)r * 128 + c] = acc[rf][cf][j] + bv;
      }
    }
  }
}

// ---------------- attention layer 2: one node per 32-lane HALF-wave ----------------
// (shfl offsets <=16 stay within each 32-lane half; eliminates R1-R15's 2x
// duplicated gathers from 64-lane waves)
__global__ __launch_bounds__(256)
void attn2_kernel(const float* __restrict__ qkvs2, const unsigned short* __restrict__ e2b,
                  const int* __restrict__ srcs, const int* __restrict__ rowptr,
                  float* __restrict__ outp) {
  const int n = blockIdx.x * 8 + (threadIdx.x >> 5);
  if (n >= N_NODES) return;
  const int c = threadIdx.x & 31;
  const int beg = rowptr[n], end = rowptr[n + 1];
  const float qv = qkvs2[(size_t)n * 128 + c];

  float m0=-INFINITY,d0=0,x0=0;
  float m1=-INFINITY,d1=0,x1=0;
  float m2=-INFINITY,d2=0,x2=0;
  float m3=-INFINITY,d3=0,x3=0;

  auto step = [&](int i, float& m, float& d, float& a) {
    const int s = srcs[i];
    const float ev = bf2f(e2b[(size_t)i * 32 + c]);
    float p = qv * (qkvs2[(size_t)s * 128 + 32 + c] + ev);
    const float v = qkvs2[(size_t)s * 128 + 64 + c] + ev;
#pragma unroll
    for (int off = 16; off; off >>= 1) p += __shfl_xor(p, off);
    p *= 0.17677669529663687f;
    const float mn = fmaxf(m, p);
    const float sc = __expf(m - mn), w = __expf(p - mn);
    d = d * sc + w; a = a * sc + w * v; m = mn;
  };

  int i = beg;
  for (; i + 3 < end; i += 4) {
    step(i, m0, d0, x0);
    step(i + 1, m1, d1, x1);
    step(i + 2, m2, d2, x2);
    step(i + 3, m3, d3, x3);
  }
  for (; i < end; ++i) step(i, m0, d0, x0);

  auto merge = [&](float& m, float& d, float& a, float mB, float dB, float b) {
    if (mB == -INFINITY) return;
    const float M = fmaxf(m, mB);
    const float sA = __expf(m - M), sB = __expf(mB - M);
    d = d * sA + dB * sB; a = a * sA + b * sB; m = M;
  };
  merge(m0, d0, x0, m1, d1, x1);
  merge(m2, d2, x2, m3, d3, x3);
  merge(m0, d0, x0, m2, d2, x2);

  float o = x0 / (d0 + 1e-16f) + qkvs2[(size_t)n * 128 + 96 + c];
  outp[(size_t)n * 32 + c] = fmaxf(o, 0.f);
}

// ---------------- launcher ----------------
extern "C" void kernel_launch(void* const* d_in, const int* in_sizes, int n_in,
                              void* d_out, int out_size, void* d_ws, size_t ws_size,
                              hipStream_t stream) {
  const float* x   = (const float*)d_in[0];
  const float* lu  = (const float*)d_in[1];
  const int*   ei  = (const int*)d_in[2];
  const float* tt  = (const float*)d_in[3];
  const float* msg = (const float*)d_in[4];
  const float* tw  = (const float*)d_in[5];
  const float* tb  = (const float*)d_in[6];
  const float* Wq1 = (const float*)d_in[7];  const float* bq1 = (const float*)d_in[8];
  const float* Wk1 = (const float*)d_in[9];  const float* bk1 = (const float*)d_in[10];
  const float* Wv1 = (const float*)d_in[11]; const float* bv1 = (const float*)d_in[12];
  const float* We1 = (const float*)d_in[13];
  const float* Ws1 = (const float*)d_in[14]; const float* bs1 = (const float*)d_in[15];
  const float* Wq2 = (const float*)d_in[16]; const float* bq2 = (const float*)d_in[17];
  const float* Wk2 = (const float*)d_in[18]; const float* bk2 = (const float*)d_in[19];
  const float* Wv2 = (const float*)d_in[20]; const float* bv2 = (const float*)d_in[21];
  const float* We2 = (const float*)d_in[22];
  const float* Ws2 = (const float*)d_in[23]; const float* bs2 = (const float*)d_in[24];

  const int* srcp = ei;
  const int* dstp = ei + N_EDGES;

  char* p = (char*)d_ws;
  auto alloc = [&](size_t bytes) -> char* {
    char* r = p;
    p += (bytes + 255) & ~(size_t)255;
    return r;
  };
  int*   deg     = (int*)alloc((size_t)N_NODES * 4);
  int*   fill    = (int*)alloc((size_t)N_NODES * 4);
  int*   rowptr  = (int*)alloc((size_t)(N_NODES + 1) * 4);
  int*   srcs    = (int*)alloc((size_t)N_EDGES * 4);
  int*   dsts    = (int*)alloc((size_t)N_EDGES * 4);
  int*   eidA    = (int*)alloc((size_t)N_EDGES * 4);
  float* rel_s   = (float*)alloc((size_t)N_EDGES * 4);
  unsigned short* xa   = (unsigned short*)alloc((size_t)RT1 * 32768);
  unsigned short* W1f  = (unsigned short*)alloc((size_t)8 * 64 * 1024);
  unsigned short* We1f = (unsigned short*)alloc((size_t)8 * 16 * 1024);
  unsigned short* W2f  = (unsigned short*)alloc((size_t)8 * 8 * 1024);
  unsigned short* We2f = (unsigned short*)alloc((size_t)8 * 4 * 1024);
  float* bcat1  = (float*)alloc(1024 * 4);
  float* bcat2  = (float*)alloc(128 * 4);
  float* qf     = (float*)alloc((size_t)N_NODES * 256 * 4);
  unsigned short* kvb = (unsigned short*)alloc((size_t)N_NODES * 512 * 2);
  float* sf     = (float*)alloc((size_t)N_NODES * 256 * 4);
  char*  segrec = (char*)alloc((size_t)N_NODES * MAXSEG * SEGSTRIDE);   // 92 MB
  float* qkvs2  = (float*)alloc((size_t)N_NODES * 128 * 4);
  unsigned short* e2b = (unsigned short*)alloc((size_t)N_EDGES * 32 * 2);
  float* outp   = (float*)d_out;

  hipMemsetAsync(deg, 0, (size_t)N_NODES * 4, stream);
  hipMemsetAsync(fill, 0, (size_t)N_NODES * 4, stream);

  count_kernel<<<625, 256, 0, stream>>>(dstp, deg, N_EDGES);
  scan_kernel<<<1, 1024, 0, stream>>>(deg, rowptr, N_NODES);
  scatter_kernel<<<625, 256, 0, stream>>>(lu, tt, srcp, dstp, rowptr, fill,
                                          srcs, dsts, eidA, rel_s, N_EDGES);

  conv_all_kernel<<<ceildiv(CONVX_T + 369792, 256), 256, 0, stream>>>(
      x, xa, Wq1, Wk1, Wv1, Ws1, We1, Wq2, Wk2, Wv2, Ws2, We2,
      bq1, bk1, bv1, bs1, bq2, bk2, bv2, bs2,
      W1f, We1f, W2f, We2f, bcat1, bcat2);

  // node1 FIRST (edge_fused consumes qf/kvb — kernel boundary = synchronization)
  node1_gemm<<<RT1 * 4, 512, 0, stream>>>(xa, W1f, bcat1, qf, kvb, sf);

  // edge GEMM + fused layer-1 attention (R14 core, q-dedup epilogue)
  edge_fused<<<RTE, 512, 0, stream>>>(
      qf, kvb, We1f, We2f, segrec, e2b,
      rel_s, tw, tb, msg, eidA, srcs, dsts, rowptr);

  // merge + layer-2 node GEMM fused
  node2_fused<<<RT1, 256, 0, stream>>>(segrec, rowptr, sf, W2f, bcat2, qkvs2);
  attn2_kernel<<<ceildiv(N_NODES, 8), 256, 0, stream>>>(qkvs2, e2b, srcs, rowptr, outp);
}